// Round 1
// baseline (60.589 us; speedup 1.0000x reference)
//
#include <hip/hip_runtime.h>

// Problem constants (from reference): N=8192, D=1024, E=8192, K=16.
#define NROWS 8192
#define DDIM  1024
#define EEDGE 8192
#define KNB   16

// Kernel 1: s1[i] = sent[i,:]·w1 + b ; s2[i] = sent[i,:]·w2
// One 64-lane wave per row; 4 waves (256 threads) per block.
// Each lane reads 4 float4 (16 floats) of the row; w1/w2 (8 KiB) stay cached.
__global__ __launch_bounds__(256) void dots_kernel(const float* __restrict__ sent,
                                                   const float* __restrict__ W,
                                                   const float* __restrict__ b,
                                                   float* __restrict__ s1,
                                                   float* __restrict__ s2) {
    int gwave = (blockIdx.x * 256 + threadIdx.x) >> 6;   // global wave id = row
    int lane  = threadIdx.x & 63;
    if (gwave >= NROWS) return;
    const float4* row = reinterpret_cast<const float4*>(sent + (size_t)gwave * DDIM);
    const float4* w1v = reinterpret_cast<const float4*>(W);
    const float4* w2v = reinterpret_cast<const float4*>(W + DDIM);
    float a1 = 0.f, a2 = 0.f;
#pragma unroll
    for (int it = 0; it < 4; ++it) {
        int idx = lane + it * 64;          // float4 index within row (256 total)
        float4 r  = row[idx];
        float4 x1 = w1v[idx];
        float4 x2 = w2v[idx];
        a1 += r.x * x1.x + r.y * x1.y + r.z * x1.z + r.w * x1.w;
        a2 += r.x * x2.x + r.y * x2.y + r.z * x2.z + r.w * x2.w;
    }
    // 64-lane butterfly reduce
#pragma unroll
    for (int off = 32; off > 0; off >>= 1) {
        a1 += __shfl_xor(a1, off, 64);
        a2 += __shfl_xor(a2, off, 64);
    }
    if (lane == 0) {
        s1[gwave] = a1 + b[0];   // fold bias into s1
        s2[gwave] = a2;
    }
}

// Kernel 2: pair_score[e, k-1] = s1[edge[e,0]] + s2[edge[e,k]]
__global__ __launch_bounds__(256) void pair_kernel(const int* __restrict__ edge,
                                                   const float* __restrict__ s1,
                                                   const float* __restrict__ s2,
                                                   float* __restrict__ pair) {
    int idx = blockIdx.x * 256 + threadIdx.x;
    if (idx >= EEDGE * (KNB - 1)) return;
    int e = idx / (KNB - 1);
    int k = idx - e * (KNB - 1) + 1;
    int c = edge[e * KNB];
    int n = edge[e * KNB + k];
    pair[idx] = s1[c] + s2[n];
}

// Kernel 3: all_score[i,j] = s1[i] + s2[j]   (b already folded into s1)
// One block per row; 256 threads × 8 float4 stores = 8192 floats/row.
__global__ __launch_bounds__(256) void all_kernel(const float* __restrict__ s1,
                                                  const float* __restrict__ s2,
                                                  float* __restrict__ out) {
    int row = blockIdx.x;
    float v1 = s1[row];
    const float4* s2v = reinterpret_cast<const float4*>(s2);
    float4* o = reinterpret_cast<float4*>(out + (size_t)row * NROWS);
#pragma unroll
    for (int it = 0; it < 8; ++it) {
        int j = threadIdx.x + it * 256;    // float4 index within row (2048 total)
        float4 v = s2v[j];
        o[j] = make_float4(v1 + v.x, v1 + v.y, v1 + v.z, v1 + v.w);
    }
}

extern "C" void kernel_launch(void* const* d_in, const int* in_sizes, int n_in,
                              void* d_out, int out_size, void* d_ws, size_t ws_size,
                              hipStream_t stream) {
    const float* sent = (const float*)d_in[0];   // (N, D) f32
    const float* W    = (const float*)d_in[1];   // (2D,)  f32
    const float* b    = (const float*)d_in[2];   // (1,)   f32
    const int*   edge = (const int*)  d_in[3];   // (E, K) i32

    float* out  = (float*)d_out;
    float* pair = out;                              // E*(K-1) floats
    float* alls = out + (size_t)EEDGE * (KNB - 1);  // N*N floats

    float* s1 = (float*)d_ws;        // N floats
    float* s2 = s1 + NROWS;          // N floats (needs 64 KiB of d_ws)

    dots_kernel<<<NROWS / 4, 256, 0, stream>>>(sent, W, b, s1, s2);
    pair_kernel<<<(EEDGE * (KNB - 1) + 255) / 256, 256, 0, stream>>>(edge, s1, s2, pair);
    all_kernel<<<NROWS, 256, 0, stream>>>(s1, s2, alls);
}

// Round 3
// 59.936 us; speedup vs baseline: 1.0109x; 1.0109x over previous
//
#include <hip/hip_runtime.h>

// Problem constants (from reference): N=8192, D=1024, E=8192, K=16.
#define NROWS 8192
#define DDIM  1024
#define EEDGE 8192
#define KNB   16

typedef float f32x4 __attribute__((ext_vector_type(4)));

// Kernel 1: s1[i] = sent[i,:]·w1 + b ; s2[i] = sent[i,:]·w2
// One 64-lane wave per row; 4 waves (256 threads) per block.
// sent rows are streamed (no reuse) -> nontemporal loads; W (8 KiB) stays cached.
__global__ __launch_bounds__(256) void dots_kernel(const float* __restrict__ sent,
                                                   const float* __restrict__ W,
                                                   const float* __restrict__ b,
                                                   float* __restrict__ s1,
                                                   float* __restrict__ s2) {
    int gwave = (blockIdx.x * 256 + threadIdx.x) >> 6;   // global wave id = row
    int lane  = threadIdx.x & 63;
    if (gwave >= NROWS) return;
    const f32x4* row = reinterpret_cast<const f32x4*>(sent + (size_t)gwave * DDIM);
    const f32x4* w1v = reinterpret_cast<const f32x4*>(W);
    const f32x4* w2v = reinterpret_cast<const f32x4*>(W + DDIM);
    float a1 = 0.f, a2 = 0.f;
#pragma unroll
    for (int it = 0; it < 4; ++it) {
        int idx = lane + it * 64;          // f32x4 index within row (256 total)
        f32x4 r  = __builtin_nontemporal_load(&row[idx]);
        f32x4 x1 = w1v[idx];
        f32x4 x2 = w2v[idx];
        a1 += r.x * x1.x + r.y * x1.y + r.z * x1.z + r.w * x1.w;
        a2 += r.x * x2.x + r.y * x2.y + r.z * x2.z + r.w * x2.w;
    }
    // 64-lane butterfly reduce
#pragma unroll
    for (int off = 32; off > 0; off >>= 1) {
        a1 += __shfl_xor(a1, off, 64);
        a2 += __shfl_xor(a2, off, 64);
    }
    if (lane == 0) {
        s1[gwave] = a1 + b[0];   // fold bias into s1
        s2[gwave] = a2;
    }
}

// Kernel 2 (fused): block `row` writes all_score[row, :] with nt f32x4 stores,
// and threads 0..14 also compute pair_score[row, :] (edge row `row`).
__global__ __launch_bounds__(256) void fused_kernel(const int* __restrict__ edge,
                                                    const float* __restrict__ s1,
                                                    const float* __restrict__ s2,
                                                    float* __restrict__ pair,
                                                    float* __restrict__ alls) {
    int row = blockIdx.x;
    int t   = threadIdx.x;

    if (t < KNB - 1) {
        int c = edge[row * KNB];
        int n = edge[row * KNB + 1 + t];
        pair[row * (KNB - 1) + t] = s1[c] + s2[n];
    }

    float v1 = s1[row];   // b already folded into s1
    const f32x4* s2v = reinterpret_cast<const f32x4*>(s2);
    f32x4* o = reinterpret_cast<f32x4*>(alls + (size_t)row * NROWS);
#pragma unroll
    for (int it = 0; it < 8; ++it) {
        int j = t + it * 256;              // f32x4 index within row (2048 total)
        f32x4 v = s2v[j];
        f32x4 r = v + v1;                  // ext_vector: scalar broadcast add
        __builtin_nontemporal_store(r, &o[j]);
    }
}

extern "C" void kernel_launch(void* const* d_in, const int* in_sizes, int n_in,
                              void* d_out, int out_size, void* d_ws, size_t ws_size,
                              hipStream_t stream) {
    const float* sent = (const float*)d_in[0];   // (N, D) f32
    const float* W    = (const float*)d_in[1];   // (2D,)  f32
    const float* b    = (const float*)d_in[2];   // (1,)   f32
    const int*   edge = (const int*)  d_in[3];   // (E, K) i32

    float* out  = (float*)d_out;
    float* pair = out;                              // E*(K-1) floats
    float* alls = out + (size_t)EEDGE * (KNB - 1);  // N*N floats (f32x4-aligned)

    float* s1 = (float*)d_ws;        // N floats
    float* s2 = s1 + NROWS;          // N floats (needs 64 KiB of d_ws)

    dots_kernel<<<NROWS / 4, 256, 0, stream>>>(sent, W, b, s1, s2);
    fused_kernel<<<NROWS, 256, 0, stream>>>(edge, s1, s2, pair, alls);
}